// Round 5
// baseline (1206.995 us; speedup 1.0000x reference)
//
#include <hip/hip_runtime.h>
#include <math.h>

#define N_TOK 65536
#define HID   256
#define FFDIM 1024
#define EPS_LN 1e-5f
#define RBLOCKS 256

typedef __bf16 bf16x8 __attribute__((ext_vector_type(8)));
typedef float  f32x4  __attribute__((ext_vector_type(4)));
typedef unsigned short u16x8 __attribute__((ext_vector_type(8)));

__device__ __forceinline__ float gelu_f(float x) {
    return 0.5f * x * (1.0f + erff(x * 0.70710678118654752f));
}
__device__ __forceinline__ float bf2f(unsigned short u) {
    return __uint_as_float(((unsigned int)u) << 16);
}
__device__ __forceinline__ unsigned short f2bf(float f) {
    unsigned int x = __float_as_uint(f);
    unsigned int r = ((x >> 16) & 1u) + 0x7fffu;
    return (unsigned short)((x + r) >> 16);
}
// async global->LDS, 16B per lane; LDS dest = wave-uniform base + lane*16
__device__ __forceinline__ void gload16(const void* g, void* l) {
    __builtin_amdgcn_global_load_lds(
        (const __attribute__((address_space(1))) void*)g,
        (__attribute__((address_space(3))) void*)l, 16, 0, 0);
}

// ---------------- weight fp32 [L,K,M] -> bf16 transposed [L,M,K] --------------
__global__ __launch_bounds__(256) void wconv(
    const float* __restrict__ src, unsigned short* __restrict__ dst,
    const int K, const int M)
{
    const size_t lo = (size_t)blockIdx.z * K * M;
    __shared__ float t[32][33];
    const int r  = threadIdx.x >> 3;
    const int c0 = (threadIdx.x & 7) * 4;
    const int bk = blockIdx.x * 32;
    const int bm = blockIdx.y * 32;
    const float4 v4 = *(const float4*)(src + lo + (size_t)(bk + r) * M + bm + c0);
    t[r][c0] = v4.x; t[r][c0+1] = v4.y; t[r][c0+2] = v4.z; t[r][c0+3] = v4.w;
    __syncthreads();
    ushort4 o;
    o.x = f2bf(t[c0+0][r]);
    o.y = f2bf(t[c0+1][r]);
    o.z = f2bf(t[c0+2][r]);
    o.w = f2bf(t[c0+3][r]);
    *(ushort4*)(dst + lo + (size_t)(bm + r) * K + bk + c0) = o;
}

// ---------------- fused LN stats + normalize -> two bf16 outputs --------------
__global__ __launch_bounds__(256) void ln_dual(
    const float* __restrict__ h,
    const float* __restrict__ gq, const float* __restrict__ bq,
    const float* __restrict__ gkv, const float* __restrict__ bkv,
    unsigned short* __restrict__ lnq, unsigned short* __restrict__ lnkv)
{
    const int row  = blockIdx.x * 4 + (threadIdx.x >> 6);
    const int lane = threadIdx.x & 63;
    const size_t base = (size_t)row * HID + lane * 4;
    const float4 xv = *(const float4*)(h + base);
    float s  = xv.x + xv.y + xv.z + xv.w;
    float s2 = fmaf(xv.x, xv.x, fmaf(xv.y, xv.y, fmaf(xv.z, xv.z, xv.w * xv.w)));
    #pragma unroll
    for (int off = 32; off > 0; off >>= 1) {
        s  += __shfl_xor(s, off, 64);
        s2 += __shfl_xor(s2, off, 64);
    }
    const float m   = s * (1.0f / HID);
    const float var = fmaxf(s2 * (1.0f / HID) - m * m, 0.f);
    const float rs  = rsqrtf(var + EPS_LN);
    const float n0 = (xv.x - m) * rs, n1 = (xv.y - m) * rs;
    const float n2 = (xv.z - m) * rs, n3 = (xv.w - m) * rs;
    const int c = lane * 4;
    float4 g4 = *(const float4*)(gq + c);
    float4 b4 = *(const float4*)(bq + c);
    ushort4 o;
    o.x = f2bf(fmaf(n0, g4.x, b4.x));
    o.y = f2bf(fmaf(n1, g4.y, b4.y));
    o.z = f2bf(fmaf(n2, g4.z, b4.z));
    o.w = f2bf(fmaf(n3, g4.w, b4.w));
    *(ushort4*)(lnq + base) = o;
    g4 = *(const float4*)(gkv + c);
    b4 = *(const float4*)(bkv + c);
    o.x = f2bf(fmaf(n0, g4.x, b4.x));
    o.y = f2bf(fmaf(n1, g4.y, b4.y));
    o.z = f2bf(fmaf(n2, g4.z, b4.z));
    o.w = f2bf(fmaf(n3, g4.w, b4.w));
    *(ushort4*)(lnkv + base) = o;
}

__global__ __launch_bounds__(256) void ln_single(
    const float* __restrict__ h,
    const float* __restrict__ g, const float* __restrict__ b,
    unsigned short* __restrict__ lno)
{
    const int row  = blockIdx.x * 4 + (threadIdx.x >> 6);
    const int lane = threadIdx.x & 63;
    const size_t base = (size_t)row * HID + lane * 4;
    const float4 xv = *(const float4*)(h + base);
    float s  = xv.x + xv.y + xv.z + xv.w;
    float s2 = fmaf(xv.x, xv.x, fmaf(xv.y, xv.y, fmaf(xv.z, xv.z, xv.w * xv.w)));
    #pragma unroll
    for (int off = 32; off > 0; off >>= 1) {
        s  += __shfl_xor(s, off, 64);
        s2 += __shfl_xor(s2, off, 64);
    }
    const float m   = s * (1.0f / HID);
    const float var = fmaxf(s2 * (1.0f / HID) - m * m, 0.f);
    const float rs  = rsqrtf(var + EPS_LN);
    const int c = lane * 4;
    const float4 g4 = *(const float4*)(g + c);
    const float4 b4 = *(const float4*)(b + c);
    ushort4 o;
    o.x = f2bf(fmaf((xv.x - m) * rs, g4.x, b4.x));
    o.y = f2bf(fmaf((xv.y - m) * rs, g4.y, b4.y));
    o.z = f2bf(fmaf((xv.z - m) * rs, g4.z, b4.z));
    o.w = f2bf(fmaf((xv.w - m) * rs, g4.w, b4.w));
    *(ushort4*)(lno + base) = o;
}

// ---------------- bf16 MFMA GEMM (m97-style): C = A[N,K] @ Wt[M,K]^T + bias ---
// 128x128 tile, BK=64, double-buffered LDS, global_load_lds 16B staging with
// XOR-swizzle (linear LDS dest + inverse-swizzled global source + swizzled read).
// Stored chunk p of row r holds logical k-chunk p^(r&7); read chunk c at c^(r&7).
template<int K, bool GELU_EP, bool RES, bool CBF16>
__global__ __launch_bounds__(256, 2) void mfma_gemm(
    const unsigned short* __restrict__ A,
    const unsigned short* __restrict__ Wt,
    const float* __restrict__ bias,
    const float* __restrict__ res,
    void* __restrict__ C, const int M)
{
    constexpr int KT = K / 64;
    __shared__ __align__(16) unsigned short Abuf[2][128 * 64];
    __shared__ __align__(16) unsigned short Bbuf[2][128 * 64];
    const int tid  = threadIdx.x;
    const int lane = tid & 63;
    const int wv   = tid >> 6;
    const int bn = blockIdx.x * 128;   // col block (fast dim -> A-panel L2 reuse)
    const int bm = blockIdx.y * 128;   // row block
    // staging: wave wv covers tile rows [wv*32, wv*32+32), 4 instrs x 8 rows.
    // lane l lands at LDS byte (l>>3)*128 + (l&7)*16 within its 8-row group.
    const int srow = (wv << 5) + (lane >> 3);
    const int schk = (lane & 7) ^ ((lane >> 3) & 7);     // inverse-swizzled source
    const char* Asrc = (const char*)(A  + (size_t)(bm + srow) * K) + schk * 16;
    const char* Bsrc = (const char*)(Wt + (size_t)(bn + srow) * K) + schk * 16;

    const int lrow = lane & 15;
    const int kgrp = lane >> 4;
    const int wr = (wv >> 1) << 6;
    const int wc = (wv & 1) << 6;

    f32x4 acc[4][4];
    #pragma unroll
    for (int i = 0; i < 4; ++i)
        #pragma unroll
        for (int j = 0; j < 4; ++j)
            acc[i][j] = (f32x4){0.f, 0.f, 0.f, 0.f};

    auto STAGE = [&](int b, int kt) {
        const char* as = Asrc + kt * 128;   // kt*64 bf16 = 128B
        const char* bs = Bsrc + kt * 128;
        char* ad = (char*)&Abuf[b][0] + (wv << 12);
        char* bd = (char*)&Bbuf[b][0] + (wv << 12);
        #pragma unroll
        for (int i = 0; i < 4; ++i) {
            gload16(as + (size_t)(i * 8) * (K * 2), ad + i * 1024);
            gload16(bs + (size_t)(i * 8) * (K * 2), bd + i * 1024);
        }
    };

    STAGE(0, 0);
    __syncthreads();
    for (int kt = 0; kt < KT; ++kt) {
        const int cur = kt & 1;
        if (kt + 1 < KT) STAGE(cur ^ 1, kt + 1);
        const char* Ab = (const char*)&Abuf[cur][0];
        const char* Bb = (const char*)&Bbuf[cur][0];
        #pragma unroll
        for (int ks = 0; ks < 2; ++ks) {
            const int pa = (((ks << 2) + kgrp) ^ (lrow & 7)) << 4;  // swizzled read
            bf16x8 af[4], bfr[4];
            #pragma unroll
            for (int mi = 0; mi < 4; ++mi)
                af[mi] = *(const bf16x8*)(Ab + (wr + mi * 16 + lrow) * 128 + pa);
            #pragma unroll
            for (int ni = 0; ni < 4; ++ni)
                bfr[ni] = *(const bf16x8*)(Bb + (wc + ni * 16 + lrow) * 128 + pa);
            #pragma unroll
            for (int mi = 0; mi < 4; ++mi)
                #pragma unroll
                for (int ni = 0; ni < 4; ++ni)
                    acc[mi][ni] = __builtin_amdgcn_mfma_f32_16x16x32_bf16(
                        af[mi], bfr[ni], acc[mi][ni], 0, 0, 0);
        }
        __syncthreads();
    }
    // epilogue: D[row=(lane>>4)*4+r][col=lane&15] per 16x16 fragment
    #pragma unroll
    for (int mi = 0; mi < 4; ++mi) {
        #pragma unroll
        for (int ni = 0; ni < 4; ++ni) {
            const int col = bn + wc + ni * 16 + lrow;
            const float bv = bias[col];
            #pragma unroll
            for (int r = 0; r < 4; ++r) {
                const int row = bm + wr + mi * 16 + kgrp * 4 + r;
                float v = acc[mi][ni][r] + bv;
                if (RES)     v += res[(size_t)row * M + col];
                if (GELU_EP) v  = gelu_f(v);
                if (CBF16) ((unsigned short*)C)[(size_t)row * M + col] = f2bf(v);
                else       ((float*)C)[(size_t)row * M + col] = v;
            }
        }
    }
}

// ---------------- stage-1 reduction over bf16 q/k/v (vectorized u16x8) --------
__global__ __launch_bounds__(256) void reduce_kernel(
    const unsigned short* __restrict__ q, const unsigned short* __restrict__ k,
    const unsigned short* __restrict__ v,
    float* __restrict__ pkv, float* __restrict__ pks,
    float* __restrict__ psq, float* __restrict__ psk)
{
    const int b   = blockIdx.x;
    const int tid = threadIdx.x;
    const int cg  = tid & 31;            // 32 column groups of 8
    const int ro  = tid >> 5;            // 8 row threads
    const int c   = cg * 8;
    const int r0  = b * (N_TOK / RBLOCKS);
    float kv[8] = {}, ks[8] = {};
    float sq = 0.f, sk = 0.f;
    #pragma unroll 4
    for (int i = 0; i < (N_TOK / RBLOCKS) / 8; ++i) {
        const size_t idx = (size_t)(r0 + ro + i * 8) * HID + c;
        const u16x8 q8 = *(const u16x8*)(q + idx);
        const u16x8 k8 = *(const u16x8*)(k + idx);
        const u16x8 v8 = *(const u16x8*)(v + idx);
        #pragma unroll
        for (int j = 0; j < 8; ++j) {
            const float qf = bf2f(q8[j]), kf = bf2f(k8[j]), vf = bf2f(v8[j]);
            kv[j] = fmaf(kf, vf, kv[j]);
            ks[j] += kf;
            sq = fmaf(qf, qf, sq);
            sk = fmaf(kf, kf, sk);
        }
    }
    __shared__ float lkv[8][256];
    __shared__ float lks[8][256];
    #pragma unroll
    for (int j = 0; j < 8; ++j) { lkv[ro][c + j] = kv[j]; lks[ro][c + j] = ks[j]; }
    __syncthreads();
    float skv = 0.f, sks = 0.f;
    #pragma unroll
    for (int r = 0; r < 8; ++r) { skv += lkv[r][tid]; sks += lks[r][tid]; }
    pkv[(size_t)b * HID + tid] = skv;
    pks[(size_t)b * HID + tid] = sks;
    #pragma unroll
    for (int off = 32; off > 0; off >>= 1) {
        sq += __shfl_down(sq, off, 64);
        sk += __shfl_down(sk, off, 64);
    }
    __shared__ float s1[4], s2[4];
    if ((tid & 63) == 0) { s1[tid >> 6] = sq; s2[tid >> 6] = sk; }
    __syncthreads();
    if (tid == 0) {
        psq[b] = s1[0] + s1[1] + s1[2] + s1[3];
        psk[b] = s2[0] + s2[1] + s2[2] + s2[3];
    }
}

// ---------------- stage-2 finalize -------------------------------------------
__global__ __launch_bounds__(256) void finalize_kernel(
    const float* __restrict__ pkv, const float* __restrict__ pks,
    const float* __restrict__ psq, const float* __restrict__ psk,
    float* __restrict__ kvsum, float* __restrict__ kssum, float* __restrict__ scal)
{
    const int c = threadIdx.x;
    float kv = 0.f, ks = 0.f;
    #pragma unroll 4
    for (int b = 0; b < RBLOCKS; ++b) {
        kv += pkv[(size_t)b * HID + c];
        ks += pks[(size_t)b * HID + c];
    }
    kvsum[c] = kv;
    kssum[c] = ks;
    float sq = 0.f, sk = 0.f;
    for (int b = c; b < RBLOCKS; b += 256) { sq += psq[b]; sk += psk[b]; }
    #pragma unroll
    for (int off = 32; off > 0; off >>= 1) {
        sq += __shfl_down(sq, off, 64);
        sk += __shfl_down(sk, off, 64);
    }
    __shared__ float s1[4], s2[4];
    if ((c & 63) == 0) { s1[c >> 6] = sq; s2[c >> 6] = sk; }
    __syncthreads();
    if (c == 0) {
        const float SQ = s1[0] + s1[1] + s1[2] + s1[3];
        const float SK = s2[0] + s2[1] + s2[2] + s2[3];
        scal[0] = rsqrtf(SQ * SK);
    }
}

// ---------------- attention elementwise (vectorized, in-place on q) -----------
__global__ __launch_bounds__(256) void attn_kernel(
    unsigned short* __restrict__ q, const unsigned short* __restrict__ v,
    const float* __restrict__ kvsum, const float* __restrict__ kssum,
    const float* __restrict__ scal)
{
    const int row  = blockIdx.x * 8 + (threadIdx.x >> 5);
    const int lane = threadIdx.x & 31;
    const int c = lane * 8;                      // 8 cols; head = lane>>2
    const size_t idx = (size_t)row * HID + c;
    const float inv = scal[0];
    const u16x8 q8 = *(const u16x8*)(q + idx);
    const u16x8 v8 = *(const u16x8*)(v + idx);
    float qf[8];
    float dot = 0.f;
    #pragma unroll
    for (int j = 0; j < 8; ++j) {
        qf[j] = bf2f(q8[j]);
        dot = fmaf(qf[j], kssum[c + j], dot);
    }
    dot += __shfl_xor(dot, 1, 4);                // reduce over the 4 lanes/head
    dot += __shfl_xor(dot, 2, 4);
    const float rden = 1.0f / fmaf(dot, inv, (float)N_TOK);
    u16x8 o;
    #pragma unroll
    for (int j = 0; j < 8; ++j) {
        const float num = fmaf(qf[j] * kvsum[c + j], inv, bf2f(v8[j]) * (float)N_TOK);
        o[j] = f2bf(num * rden);
    }
    *(u16x8*)(q + idx) = o;
}

extern "C" void kernel_launch(void* const* d_in, const int* in_sizes, int n_in,
                              void* d_out, int out_size, void* d_ws, size_t ws_size,
                              hipStream_t stream) {
    const float* x    = (const float*)d_in[0];
    const float* Wq   = (const float*)d_in[1];
    const float* bq   = (const float*)d_in[2];
    const float* Wk   = (const float*)d_in[3];
    const float* bk   = (const float*)d_in[4];
    const float* Wv   = (const float*)d_in[5];
    const float* bv   = (const float*)d_in[6];
    const float* Wh   = (const float*)d_in[7];
    const float* bh   = (const float*)d_in[8];
    const float* g1kv = (const float*)d_in[9];
    const float* b1kv = (const float*)d_in[10];
    const float* g1q  = (const float*)d_in[11];
    const float* b1q  = (const float*)d_in[12];
    const float* Wf1  = (const float*)d_in[13];
    const float* bf1  = (const float*)d_in[14];
    const float* Wf2  = (const float*)d_in[15];
    const float* bf2  = (const float*)d_in[16];
    const float* g2   = (const float*)d_in[17];
    const float* b2   = (const float*)d_in[18];
    float* out = (float*)d_out;

    // ---- workspace (~229.6 MiB; ws limit is 256 MiB) ----
    char* p = (char*)d_ws;
    const size_t nh = (size_t)N_TOK * HID;            // 16M elems
    unsigned short* lnq  = (unsigned short*)p;                 // 32 MiB
    unsigned short* lnkv = (unsigned short*)(p + nh * 2);      // 32 MiB
    unsigned short* qb   = (unsigned short*)(p + nh * 4);      // 32 MiB
    unsigned short* kb   = (unsigned short*)(p + nh * 6);      // 32 MiB
    unsigned short* act  = (unsigned short*)p;                 // 128 MiB overlay
    p += nh * 8;
    unsigned short* vb  = (unsigned short*)p;                  // 32 MiB
    unsigned short* lnh = vb;                                  // overlay
    p += nh * 2;
    float* hpre = (float*)p; p += nh * 4;                      // 64 MiB
    unsigned short* wtq  = (unsigned short*)p; p += (size_t)3 * HID * HID * 2;
    unsigned short* wtk  = (unsigned short*)p; p += (size_t)3 * HID * HID * 2;
    unsigned short* wtv  = (unsigned short*)p; p += (size_t)3 * HID * HID * 2;
    unsigned short* wth  = (unsigned short*)p; p += (size_t)3 * HID * HID * 2;
    unsigned short* wtf1 = (unsigned short*)p; p += (size_t)3 * HID * FFDIM * 2;
    unsigned short* wtf2 = (unsigned short*)p; p += (size_t)3 * FFDIM * HID * 2;
    float* pkv   = (float*)p; p += (size_t)RBLOCKS * HID * sizeof(float);
    float* pks   = (float*)p; p += (size_t)RBLOCKS * HID * sizeof(float);
    float* psq   = (float*)p; p += RBLOCKS * sizeof(float);
    float* psk   = (float*)p; p += RBLOCKS * sizeof(float);
    float* kvs   = (float*)p; p += HID * sizeof(float);
    float* kss   = (float*)p; p += HID * sizeof(float);
    float* scal  = (float*)p; p += 256;

    // ---- weights -> bf16 transposed [M][K], all 3 layers ----
    wconv<<<dim3(8, 8, 3),  256, 0, stream>>>(Wq,  wtq,  HID,  HID);
    wconv<<<dim3(8, 8, 3),  256, 0, stream>>>(Wk,  wtk,  HID,  HID);
    wconv<<<dim3(8, 8, 3),  256, 0, stream>>>(Wv,  wtv,  HID,  HID);
    wconv<<<dim3(8, 8, 3),  256, 0, stream>>>(Wh,  wth,  HID,  HID);
    wconv<<<dim3(8, 32, 3), 256, 0, stream>>>(Wf1, wtf1, HID,  FFDIM);
    wconv<<<dim3(32, 8, 3), 256, 0, stream>>>(Wf2, wtf2, FFDIM, HID);

    // grid: x = col-blocks (fast -> consecutive blocks share the A-panel in L2)
    const dim3 gQ(HID / 128, N_TOK / 128);     // (2, 512)
    const dim3 gF(FFDIM / 128, N_TOK / 128);   // (8, 512)

    for (int l = 0; l < 3; ++l) {
        const float* hin = (l == 0) ? x : out;
        const size_t vOff  = (size_t)l * HID;
        const size_t fbOff = (size_t)l * FFDIM;
        const size_t wO    = (size_t)l * HID * HID;
        const size_t fO    = (size_t)l * HID * FFDIM;

        ln_dual<<<N_TOK / 4, 256, 0, stream>>>(
            hin, g1q + vOff, b1q + vOff, g1kv + vOff, b1kv + vOff, lnq, lnkv);
        mfma_gemm<HID, false, false, true><<<gQ, 256, 0, stream>>>(
            lnq,  wtq + wO, bq + vOff, nullptr, qb, HID);
        mfma_gemm<HID, false, false, true><<<gQ, 256, 0, stream>>>(
            lnkv, wtk + wO, bk + vOff, nullptr, kb, HID);
        mfma_gemm<HID, false, false, true><<<gQ, 256, 0, stream>>>(
            lnkv, wtv + wO, bv + vOff, nullptr, vb, HID);
        reduce_kernel<<<RBLOCKS, 256, 0, stream>>>(qb, kb, vb, pkv, pks, psq, psk);
        finalize_kernel<<<1, 256, 0, stream>>>(pkv, pks, psq, psk, kvs, kss, scal);
        attn_kernel<<<N_TOK / 8, 256, 0, stream>>>(qb, vb, kvs, kss, scal);
        mfma_gemm<HID, false, true, false><<<gQ, 256, 0, stream>>>(
            qb, wth + wO, bh + vOff, hin, hpre, HID);
        ln_single<<<N_TOK / 4, 256, 0, stream>>>(hpre, g2 + vOff, b2 + vOff, lnh);
        mfma_gemm<HID, true, false, true><<<gF, 256, 0, stream>>>(
            lnh, wtf1 + fO, bf1 + fbOff, nullptr, act, FFDIM);
        mfma_gemm<FFDIM, false, true, false><<<gQ, 256, 0, stream>>>(
            act, wtf2 + fO, bf2 + vOff, hpre, out, HID);
    }
}